// Round 14
// baseline (473.984 us; speedup 1.0000x reference)
//
#include <hip/hip_runtime.h>
#include <hip/hip_bf16.h>
#include <cmath>
#include <complex>
#include <vector>
#include <cstring>
#include <cstdint>

// ---------------------------------------------------------------------------
// ShieldingT2Model: round 26 — r25 + per-k G-column in k_y2a's 222 path.
// B=16384, NS=64, NK=32, NL=16, HM=256, HC=128, out = (B,5) f32.
//
// r25 (404us, REGRESSED): 32-row barrier-free k_y2a spilled — WRITE 63.5MB
//   (~40MB scratch): G[25] live on top of acc[5][2](40 AGPR)+p(8)+Bfrags(16)
//   pushed past the 128-VGPR cap. Structure itself is sound (k_y0b proof;
//   compiler even DCE'd the unused sL buffer -> LDS 20KB).
// r26: 222 path computes G per-k: Gc[j5] = sum_i c222[i][j5][k]*tu[i]
//   inside the k-loop — SAME 125 FMA/chunk (25x5), BIT-IDENTICAL chains
//   (i ascending then j5 ascending), but -20 live regs at peak
//   (~90 VGPR + 48 AGPR, inside budget). Everything else byte-identical
//   to r25. Spill tripwire: k_y2a WRITE must drop to ~23.5MB.
// Chunk map (110): [0,32) merged 022/202 (v=c>>1, ks=c&1) | [32,40) 222 |
//   [40,45) 220 gram | [45,110) y000 sym pairs.
//
// MFMA layout facts (HW-verified r10, bit-identical):
//   A-frag:  A[m=lane&15][k=(lane>>4)*8+j];  B-frag: B^T[n=lane&15][k=...]
//   C/D   :  col=lane&15 (n), row=(lane>>4)*4+reg (m)
//
// ws (~31.6 MB):
//   mixed @0 (327680) | wSum @327680 (65536) | B2h @393216 (901120) |
//   B2l @1294336 (901120) | y0 @2195456 (8388608) | y2p @10584064 (20971520)
// C222 sign: majority-positive canonicalization, then flipped (r2/r3 A/B).
// ---------------------------------------------------------------------------

#define C222_FLIP -1.0f

#define MIX_WS_OFF   0
#define W202T_OFF    327680
#define B2H_OFF      393216
#define B2L_OFF      1294336
#define Y0_WS_OFF    2195456
#define Y2P_OFF      10584064

#define NCHUNK2      110

typedef __attribute__((ext_vector_type(8))) short short8;
typedef __attribute__((ext_vector_type(4))) float f32x4;

struct Coefs {
  float c222[125];   // full (2,2,2) real wigner-3j, [i][j][k]
  float d022[5];     // diag of C022[0,:,:]
  float d202[5];     // diag of C202[:,0,:]
  float d220[5];     // diag of C220[:,:,0]
  float a0, a2, b2;
};

#define FMA8(acc, wa, wb, sv) do { \
  acc[0] = fmaf((wa).x, (sv), acc[0]); \
  acc[1] = fmaf((wa).y, (sv), acc[1]); \
  acc[2] = fmaf((wa).z, (sv), acc[2]); \
  acc[3] = fmaf((wa).w, (sv), acc[3]); \
  acc[4] = fmaf((wb).x, (sv), acc[4]); \
  acc[5] = fmaf((wb).y, (sv), acc[5]); \
  acc[6] = fmaf((wb).z, (sv), acc[6]); \
  acc[7] = fmaf((wb).w, (sv), acc[7]); \
} while (0)

#define FMA4(acc, wa, sv) do { \
  acc[0] = fmaf((wa).x, (sv), acc[0]); \
  acc[1] = fmaf((wa).y, (sv), acc[1]); \
  acc[2] = fmaf((wa).z, (sv), acc[2]); \
  acc[3] = fmaf((wa).w, (sv), acc[3]); \
} while (0)

__device__ __forceinline__ float act_silu(float x) {
  return 1.679f * x / (1.0f + expf(-x));   // SILU_NORM * silu(x)
}

__device__ __forceinline__ short f2bf(float x) {
  __hip_bfloat16 h = __float2bfloat16(x);
  return *reinterpret_cast<short*>(&h);
}
__device__ __forceinline__ float bf2f(short s) {
  __hip_bfloat16 h = *reinterpret_cast<__hip_bfloat16*>(&s);
  return __bfloat162float(h);
}

// lane-linear permuted index for a 128n x 32k bf16 tile (shorts):
// frag read for channel-block nb = n>>4 is at nb*512 + (quad*16+m16)*8 + j
__device__ __forceinline__ int bperm(int n, int k) {
  return ((n >> 4) << 9) | (((((k >> 3) << 4) | (n & 15))) << 3) | (k & 7);
}

// ---------------------------------------------------------------------------
// K1: MLP -> weights -> mixed.  32 b per wg, 256 threads. (proven, unchanged)
// ---------------------------------------------------------------------------
__global__ __launch_bounds__(256) void k_prep(
    const float* __restrict__ s, const float* __restrict__ t2s,
    const float* __restrict__ w1, const float* __restrict__ w2,
    const float* __restrict__ w3, const float* __restrict__ gthr,
    float* __restrict__ mixed_ws)
{
  __shared__ float sT[64][36];    // [k][b], padded
  __shared__ float hT[256][36];   // [c][b], holds h1 then h2

  const int tid = threadIdx.x;
  const int b0  = blockIdx.x * 32;

  #pragma unroll
  for (int i = 0; i < 8; i++) {
    int flat = tid + i * 256;
    int bl = flat >> 6, k = flat & 63;
    sT[k][bl] = s[(size_t)(b0 + bl) * 64 + k];
  }
  __syncthreads();

  const int cg = tid & 31, bg = tid >> 5;
  const int c0 = cg * 8, bb0 = bg * 4;

  float acc[4][8];
  #pragma unroll
  for (int j = 0; j < 4; j++)
    #pragma unroll
    for (int i = 0; i < 8; i++) acc[j][i] = 0.f;

  for (int k = 0; k < 64; k++) {
    float4 bv = *(const float4*)&sT[k][bb0];
    float4 wa = *(const float4*)&w1[k * 256 + c0];
    float4 wb = *(const float4*)&w1[k * 256 + c0 + 4];
    const float bvv[4] = {bv.x, bv.y, bv.z, bv.w};
    #pragma unroll
    for (int j = 0; j < 4; j++) { FMA8(acc[j], wa, wb, bvv[j]); }
  }
  #pragma unroll
  for (int j = 0; j < 4; j++)
    #pragma unroll
    for (int i = 0; i < 8; i++)
      hT[c0 + i][bb0 + j] = act_silu(acc[j][i] * 0.125f);
  __syncthreads();

  float acc2[4][8];
  #pragma unroll
  for (int j = 0; j < 4; j++)
    #pragma unroll
    for (int i = 0; i < 8; i++) acc2[j][i] = 0.f;

  for (int k = 0; k < 256; k++) {
    float4 bv = *(const float4*)&hT[k][bb0];
    float4 wa = *(const float4*)&w2[k * 256 + c0];
    float4 wb = *(const float4*)&w2[k * 256 + c0 + 4];
    const float bvv[4] = {bv.x, bv.y, bv.z, bv.w};
    #pragma unroll
    for (int j = 0; j < 4; j++) { FMA8(acc2[j], wa, wb, bvv[j]); }
  }
  __syncthreads();
  #pragma unroll
  for (int j = 0; j < 4; j++)
    #pragma unroll
    for (int i = 0; i < 8; i++)
      hT[c0 + i][bb0 + j] = act_silu(acc2[j][i] * 0.0625f);
  __syncthreads();

  const int jj  = tid & 31;
  const int blg = tid >> 5;
  float acc3[4] = {0.f, 0.f, 0.f, 0.f};
  for (int k = 0; k < 256; k++) {
    float wv  = w3[k * 32 + jj];
    float4 hv = *(const float4*)&hT[k][blg * 4];
    acc3[0] = fmaf(hv.x, wv, acc3[0]);
    acc3[1] = fmaf(hv.y, wv, acc3[1]);
    acc3[2] = fmaf(hv.z, wv, acc3[2]);
    acc3[3] = fmaf(hv.w, wv, acc3[3]);
  }
  const float thrv = gthr[jj];
  #pragma unroll
  for (int r = 0; r < 4; r++) {
    int bl = blg * 4 + r;
    int b  = b0 + bl;
    float rel = acc3[r] * 0.0625f;
    const float* tp = t2s + (size_t)(b * 32 + jj) * 5;
    float tv0 = tp[0], tv1 = tp[1], tv2 = tp[2], tv3 = tp[3], tv4 = tp[4];
    float mag  = sqrtf(tv0*tv0 + tv1*tv1 + tv2*tv2 + tv3*tv3 + tv4*tv4);
    float gate = mag / (mag + thrv);
    float w = rel * gate * 0.17677669529663687f;  // 1/sqrt(32)
    float pm0 = w*tv0, pm1 = w*tv1, pm2 = w*tv2, pm3 = w*tv3, pm4 = w*tv4;
    #pragma unroll
    for (int off = 16; off >= 1; off >>= 1) {
      pm0 += __shfl_xor(pm0, off);
      pm1 += __shfl_xor(pm1, off);
      pm2 += __shfl_xor(pm2, off);
      pm3 += __shfl_xor(pm3, off);
      pm4 += __shfl_xor(pm4, off);
    }
    if (jj == 0) {
      float* mp = mixed_ws + (size_t)b * 5;
      mp[0] = pm0; mp[1] = pm1; mp[2] = pm2; mp[3] = pm3; mp[4] = pm4;
    }
  }
}

// ---------------------------------------------------------------------------
// K2: weight prep -> single B2 chunk stream (110 chunks of 4096 bf16 hi/lo),
// lane-linear fragment order via bperm(n,k). wSum = w2022 + w2202^T.
// (unchanged from r24)
// ---------------------------------------------------------------------------
__global__ __launch_bounds__(256) void k_wprep(
    const float* __restrict__ w000,
    const float* __restrict__ w2022x,
    const float* __restrict__ w2202, float* __restrict__ wSum,
    const float* __restrict__ w022, const float* __restrict__ w202,
    const float* __restrict__ w222, const float* __restrict__ w220,
    short* __restrict__ B2h, short* __restrict__ B2l)
{
  const int tid = threadIdx.x;
  const int blk = blockIdx.x;
  if (blk < 64) {
    int u = blk;
    int base = u * 64 - (u * (u - 1)) / 2;
    int n = (64 - u) * 128;
    for (int idx = tid; idx < n; idx += 256) {
      int t = idx >> 7, wc = idx & 127;
      int v = u + t;
      int p = base + t;
      float val = w000[(size_t)(u * 64 + v) * 128 + wc];
      if (v > u) val += w000[(size_t)(v * 64 + u) * 128 + wc];
      size_t off = (size_t)(45 + (p >> 5)) * 4096 + bperm(wc, p & 31);
      short hs = f2bf(val);
      B2h[off] = hs;
      B2l[off] = f2bf(val - bf2f(hs));
    }
  } else if (blk < 128) {
    int idx = (blk - 64) * 256 + tid;  // 16384
    int u = idx >> 7, v = idx & 127;
    wSum[v * 128 + u] = w2022x[(size_t)v * 128 + u] + w2202[(size_t)u * 128 + v];
  } else {
    int c = blk - 128;                 // 0..44
    #pragma unroll
    for (int i = 0; i < 16; i++) {
      int e = i * 256 + tid;           // 0..4095 (target, permuted index)
      int nb = e >> 9;
      int ln = (e >> 3) & 63;
      int j  = e & 7;
      int w  = nb * 16 + (ln & 15);    // channel n
      int kk = ((ln >> 4) << 3) | j;   // K index 0..31
      float V = 0.f;
      if (c < 32) {
        int v = c >> 1, u = (c & 1) * 32 + kk;
        V = w022[(size_t)(u * 16 + v) * 128 + w]
          + w202[(size_t)(v * 64 + u) * 128 + w];
      } else if (c < 40) {
        int K = (c - 32) * 32 + kk;
        int u = K >> 4, v = K & 15;
        V = w222[(size_t)(u * 16 + v) * 128 + w];
      } else {
        int q = (c - 40) * 32 + kk;
        if (q < 136) {
          int u = 0;
          while ((u + 1) * 16 - ((u + 1) * u) / 2 <= q) u++;
          int base = u * 16 - (u * (u - 1)) / 2;
          int v = u + (q - base);
          V = w220[(size_t)(u * 16 + v) * 128 + w];
          if (v > u) V += w220[(size_t)(v * 16 + u) * 128 + w];
        }
      }
      short hs = f2bf(V);
      B2h[(size_t)c * 4096 + e] = hs;
      B2l[(size_t)c * 4096 + e] = f2bf(V - bf2f(hs));
    }
  }
}

// ---------------------------------------------------------------------------
// K_y2a: chunks 0..39 (merged 022/202 + 222) -> y2p.
// r26: barrier-free 32-row structure (r25) + per-k G-column in the 222 path
// (Gc[5] instead of G[25] — same FMA count, bit-identical chains, -20 live
// regs at peak -> no spill). 512 blocks x 512 thr (bg=wave&1, nh=wave>>1,
// nf=0..1); B global->reg; ZERO __syncthreads in the chunk loop.
// ---------------------------------------------------------------------------
__global__ __launch_bounds__(512) void k_y2a(
    const float* __restrict__ s, const float* __restrict__ t2s,
    const short* __restrict__ B2h, const short* __restrict__ B2l,
    unsigned short* __restrict__ y2p, Coefs cf)
{
  __shared__ float tL[32][81];                 // 10368 B ([b][u*5+m])
  __shared__ __align__(16) short ShL[32][72];  // 4608 B (bf16 hi of s)
  __shared__ __align__(16) short SlL[32][72];  // 4608 B (bf16 lo of s)
  __shared__ float cL222[125];
  // ~20 KB -> 2+ blocks/CU

  const int tid  = threadIdx.x;
  const int b0   = blockIdx.x * 32;
  const int wave = tid >> 6;
  const int lane = tid & 63;
  const int m16  = lane & 15;
  const int quad = lane >> 4;
  const int bg   = wave & 1;           // 0..1 (16-row groups)
  const int nh   = wave >> 1;          // 0..3 (32-channel groups)
  const int bloc = bg * 16 + m16;      // A-row (m) batch-local 0..31
  const int wbase = nh * 32;

  float dk022[5];
  #pragma unroll
  for (int k = 0; k < 5; k++) dk022[k] = cf.d022[k];

  // ---- stage s (bf16 hi/lo), t, c222 (read-only after barrier) ----
  if (tid == 0) {
    #pragma unroll
    for (int i = 0; i < 125; i++) cL222[i] = cf.c222[i];
  }
  for (int idx = tid; idx < 2048; idx += 512) {
    int bl = idx >> 6, k = idx & 63;
    float x = s[(size_t)(b0 + bl) * 64 + k];
    short hs = f2bf(x);
    ShL[bl][k] = hs;
    SlL[bl][k] = f2bf(x - bf2f(hs));
  }
  for (int idx = tid; idx < 2560; idx += 512) {
    int bl = idx / 80, rem = idx - bl * 80;
    int u = rem / 5, m = rem - u * 5;
    int b = b0 + bl;
    float v;
    if (u < 15) v = t2s[(size_t)(b * 32 + u) * 5 + m];
    else {
      v = 0.f;
      for (int kk = 0; kk < 32; kk++) v += t2s[(size_t)(b * 32 + kk) * 5 + m];
    }
    tL[bl][rem] = v;     // rem == u*5+m
  }
  __syncthreads();   // the ONLY barrier

  f32x4 acc[5][2];
  #pragma unroll
  for (int k = 0; k < 5; k++) {
    acc[k][0] = 0.f; acc[k][1] = 0.f;
  }
  f32x4 p0 = 0.f, p1 = 0.f;

  // B fragment addresses (short8 units): chunk c starts at c*512
  const short8* Bh8 = (const short8*)B2h;
  const short8* Bl8 = (const short8*)B2l;
  const int off0 = (nh * 2) * 64 + lane;   // nf=0 block
  const int off1 = off0 + 64;              // nf=1 block

  for (int c = 0; c < 40; c++) {
    const size_t cb = (size_t)c * 512;
    short8 bh0 = Bh8[cb + off0];
    short8 bh1 = Bh8[cb + off1];
    short8 bl0 = Bl8[cb + off0];
    short8 bl1 = Bl8[cb + off1];

    if (c < 32) {
      // ---- merged 022+202: P[b,v,w] accumulation over K=64 (2 chunks) ----
      const int ks = c & 1;
      short8 ah = *(const short8*)&ShL[bloc][ks * 32 + quad * 8];
      short8 al = *(const short8*)&SlL[bloc][ks * 32 + quad * 8];
      p0 = __builtin_amdgcn_mfma_f32_16x16x32_bf16(ah, bh0, p0, 0, 0, 0);
      p0 = __builtin_amdgcn_mfma_f32_16x16x32_bf16(ah, bl0, p0, 0, 0, 0);
      p0 = __builtin_amdgcn_mfma_f32_16x16x32_bf16(al, bh0, p0, 0, 0, 0);
      p1 = __builtin_amdgcn_mfma_f32_16x16x32_bf16(ah, bh1, p1, 0, 0, 0);
      p1 = __builtin_amdgcn_mfma_f32_16x16x32_bf16(ah, bl1, p1, 0, 0, 0);
      p1 = __builtin_amdgcn_mfma_f32_16x16x32_bf16(al, bh1, p1, 0, 0, 0);
      if (ks) {
        // contract over this v: acc[k] += d[k]*t[b,v,k]*P   (fp32)
        const int v = c >> 1;
        #pragma unroll
        for (int r = 0; r < 4; r++) {
          const int bl = bg * 16 + quad * 4 + r;   // D-row -> batch-local
          const float* tr = &tL[bl][v * 5];
          #pragma unroll
          for (int k = 0; k < 5; k++) {
            float f = dk022[k] * tr[k];
            acc[k][0][r] += f * p0[r];
            acc[k][1][r] += f * p1[r];
          }
        }
        p0 = 0.f; p1 = 0.f;
      }
    } else {
      // ---- 222 segment: per-k G-column (Gc[5], same chains as G[25]) ----
      int cc = c - 32;
      int u  = cc * 2 + (quad >> 1);
      int vb = (quad & 1) * 8;
      float tu[5];
      #pragma unroll
      for (int i = 0; i < 5; i++) tu[i] = tL[bloc][u * 5 + i];
      #pragma unroll
      for (int k = 0; k < 5; k++) {
        float Gc[5];
        #pragma unroll
        for (int j5 = 0; j5 < 5; j5++) {
          float g = 0.f;
          #pragma unroll
          for (int i = 0; i < 5; i++)
            g = fmaf(cL222[i * 25 + j5 * 5 + k], tu[i], g);
          Gc[j5] = g;
        }
        short8 ah, al;
        #pragma unroll
        for (int j = 0; j < 8; j++) {
          float q = 0.f;
          #pragma unroll
          for (int j5 = 0; j5 < 5; j5++)
            q = fmaf(Gc[j5], tL[bloc][(vb + j) * 5 + j5], q);
          short hs = f2bf(q);
          ah[j] = hs;
          al[j] = f2bf(q - bf2f(hs));
        }
        acc[k][0] = __builtin_amdgcn_mfma_f32_16x16x32_bf16(ah, bh0, acc[k][0], 0, 0, 0);
        acc[k][0] = __builtin_amdgcn_mfma_f32_16x16x32_bf16(ah, bl0, acc[k][0], 0, 0, 0);
        acc[k][0] = __builtin_amdgcn_mfma_f32_16x16x32_bf16(al, bh0, acc[k][0], 0, 0, 0);
        acc[k][1] = __builtin_amdgcn_mfma_f32_16x16x32_bf16(ah, bh1, acc[k][1], 0, 0, 0);
        acc[k][1] = __builtin_amdgcn_mfma_f32_16x16x32_bf16(ah, bl1, acc[k][1], 0, 0, 0);
        acc[k][1] = __builtin_amdgcn_mfma_f32_16x16x32_bf16(al, bh1, acc[k][1], 0, 0, 0);
      }
    }
  }

  // ---- epilogue: D row = quad*4+r (b-local in bg), col = m16 (ch-local) ----
  #pragma unroll
  for (int nf = 0; nf < 2; nf++) {
    int ch = wbase + nf * 16 + m16;
    #pragma unroll
    for (int r = 0; r < 4; r++) {
      int b = b0 + bg * 16 + quad * 4 + r;
      #pragma unroll
      for (int k = 0; k < 5; k++)
        y2p[((size_t)b * 5 + k) * 128 + ch] = (unsigned short)f2bf(acc[k][nf][r]);
    }
  }
}

// ---------------------------------------------------------------------------
// K_y0b: chunks 40..109 (220 gram + y000 sym pairs) -> y0w.
// (unchanged from r23 — barrier-free 32-row structure)
// ---------------------------------------------------------------------------
__global__ __launch_bounds__(512) void k_y0b(
    const float* __restrict__ s, const float* __restrict__ t2s,
    const short* __restrict__ B2h, const short* __restrict__ B2l,
    float* __restrict__ y0w, Coefs cf)
{
  __shared__ float sL[32][65];                 // 8320 B
  __shared__ float tL[32][81];                 // 10368 B ([b][u*5+m])
  __shared__ unsigned char p136s[136];
  __shared__ unsigned short p16[2080];         // 4160 B
  // ~23 KB

  const int tid  = threadIdx.x;
  const int b0   = blockIdx.x * 32;
  const int wave = tid >> 6;
  const int lane = tid & 63;
  const int m16  = lane & 15;
  const int quad = lane >> 4;
  const int bg   = wave & 1;           // 0..1 (16-row groups)
  const int nh   = wave >> 1;          // 0..3 (32-channel groups)
  const int bloc = bg * 16 + m16;      // A-row (m) batch-local 0..31
  const int wbase = nh * 32;

  float dk220[5];
  #pragma unroll
  for (int k = 0; k < 5; k++) dk220[k] = cf.d220[k];

  // ---- stage s, t, pair tables (read-only after the single barrier) ----
  for (int idx = tid; idx < 2048; idx += 512) {
    int bl = idx >> 6, k = idx & 63;
    sL[bl][k] = s[(size_t)(b0 + bl) * 64 + k];
  }
  for (int idx = tid; idx < 2560; idx += 512) {
    int bl = idx / 80, rem = idx - bl * 80;
    int u = rem / 5, m = rem - u * 5;
    int b = b0 + bl;
    float v;
    if (u < 15) v = t2s[(size_t)(b * 32 + u) * 5 + m];
    else {
      v = 0.f;
      for (int kk = 0; kk < 32; kk++) v += t2s[(size_t)(b * 32 + kk) * 5 + m];
    }
    tL[bl][rem] = v;     // rem == u*5+m
  }
  if (tid < 16) {
    int u = tid;
    int base = u * 16 - (u * (u - 1)) / 2;
    for (int t = 0; t < 16 - u; t++)
      p136s[base + t] = (unsigned char)((u << 4) | (u + t));
  }
  if (tid < 64) {
    int u = tid;
    int base = u * 64 - (u * (u - 1)) / 2;
    for (int t = 0; t < 64 - u; t++)
      p16[base + t] = (unsigned short)((u << 8) | (u + t));
  }
  __syncthreads();   // the ONLY barrier

  f32x4 accY0[2];
  accY0[0] = 0.f; accY0[1] = 0.f;

  // B fragment addresses (short8 units): chunk c starts at c*512
  const short8* Bh8 = (const short8*)B2h;
  const short8* Bl8 = (const short8*)B2l;
  const int off0 = (nh * 2) * 64 + lane;   // nf=0 block
  const int off1 = off0 + 64;              // nf=1 block

  for (int c = 40; c < NCHUNK2; c++) {
    const size_t cb = (size_t)c * 512;
    short8 bh0 = Bh8[cb + off0];
    short8 bh1 = Bh8[cb + off1];
    short8 bl0 = Bl8[cb + off0];
    short8 bl1 = Bl8[cb + off1];

    short8 ah, al;
    if (c < 45) {
      // ---- 220 segment: A = gram of t (no k) ----
      int cc = c - 40;
      int qbase = cc * 32 + quad * 8;
      #pragma unroll
      for (int j = 0; j < 8; j++) {
        int q = qbase + j;
        float g = 0.f;
        if (q < 136) {
          int uv = p136s[q];
          int u = uv >> 4, v = uv & 15;
          #pragma unroll
          for (int m = 0; m < 5; m++)
            g = fmaf(dk220[m] * tL[bloc][u * 5 + m], tL[bloc][v * 5 + m], g);
        }
        short hs = f2bf(g);
        ah[j] = hs;
        al[j] = f2bf(g - bf2f(hs));
      }
    } else {
      // ---- y000 segment: A = s-pair products ----
      int pbase = (c - 45) * 32 + quad * 8;    // < 2080 always (65*32)
      #pragma unroll
      for (int j = 0; j < 8; j++) {
        int uv = p16[pbase + j];
        float x = sL[bloc][uv >> 8] * sL[bloc][uv & 255];
        short hs = f2bf(x);
        ah[j] = hs;
        al[j] = f2bf(x - bf2f(hs));
      }
    }
    accY0[0] = __builtin_amdgcn_mfma_f32_16x16x32_bf16(ah, bh0, accY0[0], 0, 0, 0);
    accY0[0] = __builtin_amdgcn_mfma_f32_16x16x32_bf16(ah, bl0, accY0[0], 0, 0, 0);
    accY0[0] = __builtin_amdgcn_mfma_f32_16x16x32_bf16(al, bh0, accY0[0], 0, 0, 0);
    accY0[1] = __builtin_amdgcn_mfma_f32_16x16x32_bf16(ah, bh1, accY0[1], 0, 0, 0);
    accY0[1] = __builtin_amdgcn_mfma_f32_16x16x32_bf16(ah, bl1, accY0[1], 0, 0, 0);
    accY0[1] = __builtin_amdgcn_mfma_f32_16x16x32_bf16(al, bh1, accY0[1], 0, 0, 0);
  }

  // ---- epilogue: D row = quad*4+r (b-local in bg), col = m16 (ch-local) ----
  #pragma unroll
  for (int nf = 0; nf < 2; nf++) {
    int ch = wbase + nf * 16 + m16;
    #pragma unroll
    for (int r = 0; r < 4; r++) {
      int b = b0 + bg * 16 + quad * 4 + r;
      y0w[(size_t)b * 128 + ch] = accY0[nf][r];
    }
  }
}

// ---------------------------------------------------------------------------
// K_fused: y0/y2 load + phase5 + epilogue. 32 b per block, 512 blocks,
// 512 threads. (unchanged from r24 — merged 022/202 over wSum + 222 tiled)
// ---------------------------------------------------------------------------
__global__ __launch_bounds__(512) void k_fused(
    const float* __restrict__ mixed_ws,
    const float* __restrict__ y0w, const unsigned short* __restrict__ y2p,
    const float* __restrict__ wSum, const float* __restrict__ w2222,
    const float* __restrict__ csc, float* __restrict__ out, Coefs cf)
{
  __shared__ __align__(16) float y0I[16][128][2];   // 16384 B
  __shared__ __align__(16) float wLd[32][128];      // 16384 B (K-tile stage)
  __shared__ float y2S[5][16][32][2];               // 20480 B (222 tile stage)
  __shared__ float cL222[125];
  __shared__ float corrAcc[32][5];
  __shared__ float pPL[32][25];
  // ~57.6 KB -> 2 blocks/CU

  const int tid = threadIdx.x;
  const int b0  = blockIdx.x * 32;

  float dk022[5];
  #pragma unroll
  for (int k = 0; k < 5; k++) dk022[k] = cf.d022[k];

  if (tid == 0) {
    #pragma unroll
    for (int i = 0; i < 125; i++) cL222[i] = cf.c222[i];
  }
  // stage y0 (a0-scaled) in interleaved-pair layout
  for (int idx = tid; idx < 4096; idx += 512) {
    int bl = idx >> 7, ch = idx & 127;
    y0I[bl >> 1][ch][bl & 1] = cf.a0 * y0w[(size_t)(b0 + bl) * 128 + ch];
  }

  const int xw = tid & 31;
  const int g  = tid >> 5;
  const int w0 = xw * 4;
  const int bA = 2 * g, bB = 2 * g + 1;
  const int srow = tid >> 4;            // 0..31 (wLd stage row)
  const int scol = (tid & 15) * 8;      // 0..120 (wLd stage col)

  // y2 fragments from ws (bf16), a2-scaled
  float y2acc[5][2][4];
  #pragma unroll
  for (int k = 0; k < 5; k++) {
    #pragma unroll
    for (int h = 0; h < 2; h++) {
      int b = b0 + 2 * g + h;
      const unsigned short* yp = y2p + ((size_t)b * 5 + k) * 128 + w0;
      ushort4 u4 = *(const ushort4*)yp;
      y2acc[k][h][0] = cf.a2 * bf2f((short)u4.x);
      y2acc[k][h][1] = cf.a2 * bf2f((short)u4.y);
      y2acc[k][h][2] = cf.a2 * bf2f((short)u4.z);
      y2acc[k][h][3] = cf.a2 * bf2f((short)u4.w);
    }
  }
  __syncthreads();   // y0I ready

  // ================= phase 5 — K-tile-staged =================
  // merged 022+202 path (wSum = w2022 + w2202^T; d022 == d202)
  {
    float gvr[2][4] = {{0.f,0.f,0.f,0.f},{0.f,0.f,0.f,0.f}};
    for (int t = 0; t < 4; t++) {
      const int u0 = t * 32;
      *(float4*)&wLd[srow][scol]     = *(const float4*)(wSum + (size_t)(u0 + srow) * 128 + scol);
      *(float4*)&wLd[srow][scol + 4] = *(const float4*)(wSum + (size_t)(u0 + srow) * 128 + scol + 4);
      __syncthreads();
      #pragma unroll 8
      for (int uu = 0; uu < 32; uu++) {
        float2 y0p = *(const float2*)&y0I[g][u0 + uu][0];
        float4 w4 = *(const float4*)&wLd[uu][w0];
        FMA4(gvr[0], w4, y0p.x);
        FMA4(gvr[1], w4, y0p.y);
      }
      __syncthreads();
    }
    #pragma unroll
    for (int k = 0; k < 5; k++) {
      float pA = gvr[0][0]*y2acc[k][0][0] + gvr[0][1]*y2acc[k][0][1]
               + gvr[0][2]*y2acc[k][0][2] + gvr[0][3]*y2acc[k][0][3];
      float pB = gvr[1][0]*y2acc[k][1][0] + gvr[1][1]*y2acc[k][1][1]
               + gvr[1][2]*y2acc[k][1][2] + gvr[1][3]*y2acc[k][1][3];
      pA += __shfl_xor(pA, 16); pA += __shfl_xor(pA, 8); pA += __shfl_xor(pA, 4);
      pA += __shfl_xor(pA, 2);  pA += __shfl_xor(pA, 1);
      pB += __shfl_xor(pB, 16); pB += __shfl_xor(pB, 8); pB += __shfl_xor(pB, 4);
      pB += __shfl_xor(pB, 2);  pB += __shfl_xor(pB, 1);
      if (xw == 0) {
        corrAcc[bA][k] = dk022[k] * pA;
        corrAcc[bB][k] = dk022[k] * pB;
      }
    }
  }
  // 222 path: all 5 zr[i] accumulated per w2222-tile; y2S per-tile stage
  {
    float zr[5][2][4];
    #pragma unroll
    for (int i = 0; i < 5; i++)
      #pragma unroll
      for (int h = 0; h < 2; h++)
        #pragma unroll
        for (int w = 0; w < 4; w++) zr[i][h][w] = 0.f;

    for (int t = 0; t < 4; t++) {
      const int u0 = t * 32;
      *(float4*)&wLd[srow][scol]     = *(const float4*)(w2222 + (size_t)(u0 + srow) * 128 + scol);
      *(float4*)&wLd[srow][scol + 4] = *(const float4*)(w2222 + (size_t)(u0 + srow) * 128 + scol + 4);
      if (w0 >= u0 && w0 < u0 + 32) {
        const int uu0 = w0 - u0;
        #pragma unroll
        for (int i = 0; i < 5; i++)
          #pragma unroll
          for (int h = 0; h < 2; h++)
            #pragma unroll
            for (int c = 0; c < 4; c++)
              y2S[i][g][uu0 + c][h] = y2acc[i][h][c];
      }
      __syncthreads();
      #pragma unroll 4
      for (int uu = 0; uu < 32; uu++) {
        float4 w4 = *(const float4*)&wLd[uu][w0];
        #pragma unroll
        for (int i = 0; i < 5; i++) {
          float ya = y2S[i][g][uu][0];
          float yb = y2S[i][g][uu][1];
          FMA4(zr[i][0], w4, ya);
          FMA4(zr[i][1], w4, yb);
        }
      }
      __syncthreads();
    }
    #pragma unroll
    for (int i = 0; i < 5; i++) {
      #pragma unroll
      for (int j = 0; j < 5; j++) {
        float pA = zr[i][0][0]*y2acc[j][0][0] + zr[i][0][1]*y2acc[j][0][1]
                 + zr[i][0][2]*y2acc[j][0][2] + zr[i][0][3]*y2acc[j][0][3];
        float pB = zr[i][1][0]*y2acc[j][1][0] + zr[i][1][1]*y2acc[j][1][1]
                 + zr[i][1][2]*y2acc[j][1][2] + zr[i][1][3]*y2acc[j][1][3];
        pA += __shfl_xor(pA, 16); pA += __shfl_xor(pA, 8); pA += __shfl_xor(pA, 4);
        pA += __shfl_xor(pA, 2);  pA += __shfl_xor(pA, 1);
        pB += __shfl_xor(pB, 16); pB += __shfl_xor(pB, 8); pB += __shfl_xor(pB, 4);
        pB += __shfl_xor(pB, 2);  pB += __shfl_xor(pB, 1);
        if (xw == 0) {
          pPL[bA][i * 5 + j] = pA;
          pPL[bB][i * 5 + j] = pB;
        }
      }
    }
  }
  __syncthreads();   // corrAcc/pPL visible to epilogue threads

  // ---- epilogue ----
  if (tid < 160) {
    int bb = tid / 5, k = tid - bb * 5;
    float c2 = 0.f;
    #pragma unroll
    for (int ii = 0; ii < 5; ii++)
      #pragma unroll
      for (int jj = 0; jj < 5; jj++)
        c2 = fmaf(cL222[ii * 25 + jj * 5 + k], pPL[bb][ii * 5 + jj], c2);
    float tot = corrAcc[bb][k] + c2;
    int b = b0 + bb;
    out[(size_t)b * 5 + k] = mixed_ws[(size_t)b * 5 + k] + csc[0] * cf.b2 * tot;
  }
}

// ---------------------------------------------------------------------------
// Host: replicate reference's wigner-3j computation (RREF null space).
// ---------------------------------------------------------------------------
namespace {

using cplx = std::complex<double>;

static void su2_gen(int l, std::vector<cplx>& Jx, std::vector<cplx>& Jy,
                    std::vector<cplx>& Jz) {
  int d = 2 * l + 1;
  Jx.assign((size_t)d * d, cplx(0, 0));
  Jy.assign((size_t)d * d, cplx(0, 0));
  Jz.assign((size_t)d * d, cplx(0, 0));
  for (int a = 0; a < d; a++) Jz[(size_t)a * d + a] = cplx(a - l, 0);
  for (int r = 1; r < d; r++) {
    double m = (r - 1) - l;
    double v = std::sqrt(l * (l + 1.0) - m * (m + 1.0));
    Jx[(size_t)r * d + (r - 1)] += cplx(v / 2, 0);
    Jx[(size_t)(r - 1) * d + r] += cplx(v / 2, 0);
    Jy[(size_t)r * d + (r - 1)] += cplx(0, -v / 2);
    Jy[(size_t)(r - 1) * d + r] += cplx(0, v / 2);
  }
}

static void real_basis(int l, std::vector<cplx>& U) {
  int d = 2 * l + 1;
  U.assign((size_t)d * d, cplx(0, 0));
  U[(size_t)l * d + l] = cplx(1, 0);
  double is2 = 1.0 / std::sqrt(2.0);
  for (int m = 1; m <= l; m++) {
    double sgn = (m % 2 == 0) ? 1.0 : -1.0;
    U[(size_t)(l + m) * d + (l + m)] = cplx(sgn * is2, 0);
    U[(size_t)(l + m) * d + (l - m)] = cplx(is2, 0);
    U[(size_t)(l - m) * d + (l - m)] = cplx(0, is2);
    U[(size_t)(l - m) * d + (l + m)] = cplx(0, -sgn * is2);
  }
}

static void real_gens(int l, std::vector<double> G[3]) {
  int d = 2 * l + 1;
  if (l == 0) { for (int a = 0; a < 3; a++) G[a].assign(1, 0.0); return; }
  std::vector<cplx> J[3];
  su2_gen(l, J[0], J[1], J[2]);
  std::vector<cplx> U;
  real_basis(l, U);
  for (int a = 0; a < 3; a++) {
    std::vector<cplx> T((size_t)d * d, cplx(0, 0));
    for (int i = 0; i < d; i++)
      for (int k = 0; k < d; k++) {
        cplx s(0, 0);
        for (int j = 0; j < d; j++)
          s += U[(size_t)i * d + j] * (cplx(0, -1) * J[a][(size_t)j * d + k]);
        T[(size_t)i * d + k] = s;
      }
    G[a].assign((size_t)d * d, 0.0);
    for (int i = 0; i < d; i++)
      for (int k = 0; k < d; k++) {
        cplx s(0, 0);
        for (int j = 0; j < d; j++)
          s += T[(size_t)i * d + j] * std::conj(U[(size_t)k * d + j]);
        G[a][(size_t)i * d + k] = s.real();
      }
  }
}

static void w3j_host(int l1, int l2, int l3, float* out) {
  int d1 = 2 * l1 + 1, d2 = 2 * l2 + 1, d3 = 2 * l3 + 1;
  int D = d1 * d2 * d3;
  std::vector<double> G1[3], G2[3], G3[3];
  real_gens(l1, G1); real_gens(l2, G2); real_gens(l3, G3);
  int R = 3 * D;
  std::vector<double> M((size_t)R * D, 0.0);
  for (int a = 0; a < 3; a++) {
    double* Ma = &M[(size_t)a * D * D];
    for (int i1 = 0; i1 < d1; i1++)
      for (int j1 = 0; j1 < d1; j1++) {
        double g = G1[a][(size_t)i1 * d1 + j1];
        if (g == 0.0) continue;
        for (int i2 = 0; i2 < d2; i2++)
          for (int i3 = 0; i3 < d3; i3++)
            Ma[(size_t)((i1 * d2 + i2) * d3 + i3) * D + ((j1 * d2 + i2) * d3 + i3)] += g;
      }
    for (int i2 = 0; i2 < d2; i2++)
      for (int j2 = 0; j2 < d2; j2++) {
        double g = G2[a][(size_t)i2 * d2 + j2];
        if (g == 0.0) continue;
        for (int i1 = 0; i1 < d1; i1++)
          for (int i3 = 0; i3 < d3; i3++)
            Ma[(size_t)((i1 * d2 + i2) * d3 + i3) * D + ((i1 * d2 + j2) * d3 + i3)] += g;
      }
    for (int i3 = 0; i3 < d3; i3++)
      for (int j3 = 0; j3 < d3; j3++) {
        double g = G3[a][(size_t)i3 * d3 + j3];
        if (g == 0.0) continue;
        for (int i1 = 0; i1 < d1; i1++)
          for (int i2 = 0; i2 < d2; i2++)
            Ma[(size_t)((i1 * d2 + i2) * d3 + i3) * D + ((i1 * d2 + i2) * d3 + j3)] += g;
      }
  }
  std::vector<int> pivcol;
  int rank = 0;
  for (int col = 0; col < D && rank < R; col++) {
    int pr = -1; double pv = 1e-9;
    for (int r = rank; r < R; r++) {
      double av = std::fabs(M[(size_t)r * D + col]);
      if (av > pv) { pv = av; pr = r; }
    }
    if (pr < 0) continue;
    if (pr != rank)
      for (int c = 0; c < D; c++) std::swap(M[(size_t)pr * D + c], M[(size_t)rank * D + c]);
    double inv = 1.0 / M[(size_t)rank * D + col];
    for (int c = 0; c < D; c++) M[(size_t)rank * D + c] *= inv;
    for (int r = 0; r < R; r++) {
      if (r == rank) continue;
      double f = M[(size_t)r * D + col];
      if (f != 0.0)
        for (int c = 0; c < D; c++) M[(size_t)r * D + c] -= f * M[(size_t)rank * D + c];
    }
    pivcol.push_back(col);
    rank++;
  }
  std::vector<char> isp(D, 0);
  for (int c : pivcol) isp[c] = 1;
  int fc = 0;
  for (int c = 0; c < D; c++) if (!isp[c]) { fc = c; break; }
  std::vector<double> x(D, 0.0);
  x[fc] = 1.0;
  for (int r = 0; r < rank; r++) x[pivcol[r]] = -M[(size_t)r * D + fc];
  double n = 0;
  for (double v : x) n += v * v;
  n = std::sqrt(n);
  for (int c = 0; c < D; c++) x[c] /= n;
  double best = 0;
  for (int c = 0; c < D; c++) { double av = std::fabs(x[c]); if (av > best) best = av; }
  double ssum = 0;
  for (int c = 0; c < D; c++) {
    double av = std::fabs(x[c]);
    if (av >= best * 0.999) ssum += (x[c] >= 0 ? 1.0 : -1.0);
  }
  double sgn = (ssum >= 0) ? 1.0 : -1.0;
  for (int c = 0; c < D; c++) out[c] = (float)(x[c] * sgn);
}

}  // namespace

// ---------------------------------------------------------------------------
extern "C" void kernel_launch(void* const* d_in, const int* in_sizes, int n_in,
                              void* d_out, int out_size, void* d_ws, size_t ws_size,
                              hipStream_t stream)
{
  (void)in_sizes; (void)n_in; (void)out_size; (void)ws_size;

  const float* s     = (const float*)d_in[0];
  const float* t2s   = (const float*)d_in[1];
  const float* w1    = (const float*)d_in[2];
  const float* w2    = (const float*)d_in[3];
  const float* w3    = (const float*)d_in[4];
  const float* gthr  = (const float*)d_in[5];
  const float* w000  = (const float*)d_in[6];
  const float* w220  = (const float*)d_in[7];
  const float* w022  = (const float*)d_in[8];
  const float* w202  = (const float*)d_in[9];
  const float* w222  = (const float*)d_in[10];
  const float* w2022 = (const float*)d_in[11];
  const float* w2202 = (const float*)d_in[12];
  const float* w2222 = (const float*)d_in[13];
  const float* csc   = (const float*)d_in[14];
  float* out = (float*)d_out;

  char* ws = (char*)d_ws;
  float* mixed_ws = (float*)(ws + MIX_WS_OFF);
  float* wSum     = (float*)(ws + W202T_OFF);
  short* B2h      = (short*)(ws + B2H_OFF);
  short* B2l      = (short*)(ws + B2L_OFF);
  float* y0_ws    = (float*)(ws + Y0_WS_OFF);
  unsigned short* y2p = (unsigned short*)(ws + Y2P_OFF);

  Coefs cf;
  {
    float c000v[1], c022v[25], c202v[25], c220v[25];
    w3j_host(0, 0, 0, c000v);
    w3j_host(0, 2, 2, c022v);
    w3j_host(2, 0, 2, c202v);
    w3j_host(2, 2, 0, c220v);
    w3j_host(2, 2, 2, cf.c222);
    for (int i = 0; i < 125; i++) cf.c222[i] *= C222_FLIP;
    for (int k = 0; k < 5; k++) {
      cf.d022[k] = c022v[k * 5 + k];
      cf.d202[k] = c202v[k * 5 + k];
      cf.d220[k] = c220v[k * 5 + k];
    }
    (void)c000v;
    cf.a0 = (float)std::sqrt(1.0 / (64.0 * 64.0 + 16.0 * 16.0));
    cf.a2 = (float)std::sqrt(5.0 / (2.0 * 64.0 * 16.0 + 16.0 * 16.0));
    cf.b2 = (float)std::sqrt(5.0 / (3.0 * 128.0 * 128.0));
  }

  hipLaunchKernelGGL(k_prep, dim3(512), dim3(256), 0, stream,
                     s, t2s, w1, w2, w3, gthr, mixed_ws);
  hipLaunchKernelGGL(k_wprep, dim3(173), dim3(256), 0, stream,
                     w000, w2022, w2202, wSum,
                     w022, w202, w222, w220, B2h, B2l);
  hipLaunchKernelGGL(k_y0b, dim3(512), dim3(512), 0, stream,
                     s, t2s, B2h, B2l, y0_ws, cf);
  hipLaunchKernelGGL(k_y2a, dim3(512), dim3(512), 0, stream,
                     s, t2s, B2h, B2l, y2p, cf);
  hipLaunchKernelGGL(k_fused, dim3(512), dim3(512), 0, stream,
                     mixed_ws, y0_ws, y2p, wSum, w2222, csc, out, cf);
}

// Round 15
// 374.208 us; speedup vs baseline: 1.2666x; 1.2666x over previous
//
#include <hip/hip_runtime.h>
#include <hip/hip_bf16.h>
#include <cmath>
#include <complex>
#include <vector>
#include <cstring>
#include <cstdint>

// ---------------------------------------------------------------------------
// ShieldingT2Model: round 27 — REVERT to r24 (best verified: 374.6us).
// B=16384, NS=64, NK=32, NL=16, HM=256, HC=128, out = (B,5) f32.
//
// r25 (404us) / r26 (474us): two attempts at a barrier-free 32-row k_y2a
//   both spilled (WRITE 63.5MB then 251MB). Mechanism: with 48 persistent
//   AGPR, the compiler's software-pipelining of global->reg B-loads
//   multiplies live fragments past the 128-VGPR cap; shrinking scratch
//   arrays just gives the scheduler more hoisting room. Barrier-free is
//   proven compatible ONLY with tiny accumulator footprints (k_y0b, 8 AGPR).
// r27 = r24 verbatim: k_y2a 64-row LDS-staged (85us, no spill), barrier-free
//   k_y0b, merged-wSum k_fused (K-tile staged), k_prep/k_wprep proven.
// Chunk map (110): [0,32) merged 022/202 (v=c>>1, ks=c&1) | [32,40) 222 |
//   [40,45) 220 gram | [45,110) y000 sym pairs.
//
// MFMA layout facts (HW-verified r10, bit-identical):
//   A-frag:  A[m=lane&15][k=(lane>>4)*8+j];  B-frag: B^T[n=lane&15][k=...]
//   C/D   :  col=lane&15 (n), row=(lane>>4)*4+reg (m)
//
// ws (~31.6 MB):
//   mixed @0 (327680) | wSum @327680 (65536) | B2h @393216 (901120) |
//   B2l @1294336 (901120) | y0 @2195456 (8388608) | y2p @10584064 (20971520)
// C222 sign: majority-positive canonicalization, then flipped (r2/r3 A/B).
// ---------------------------------------------------------------------------

#define C222_FLIP -1.0f

#define MIX_WS_OFF   0
#define W202T_OFF    327680
#define B2H_OFF      393216
#define B2L_OFF      1294336
#define Y0_WS_OFF    2195456
#define Y2P_OFF      10584064

#define NCHUNK2      110

typedef __attribute__((ext_vector_type(8))) short short8;
typedef __attribute__((ext_vector_type(4))) float f32x4;

struct Coefs {
  float c222[125];   // full (2,2,2) real wigner-3j, [i][j][k]
  float d022[5];     // diag of C022[0,:,:]
  float d202[5];     // diag of C202[:,0,:]
  float d220[5];     // diag of C220[:,:,0]
  float a0, a2, b2;
};

#define FMA8(acc, wa, wb, sv) do { \
  acc[0] = fmaf((wa).x, (sv), acc[0]); \
  acc[1] = fmaf((wa).y, (sv), acc[1]); \
  acc[2] = fmaf((wa).z, (sv), acc[2]); \
  acc[3] = fmaf((wa).w, (sv), acc[3]); \
  acc[4] = fmaf((wb).x, (sv), acc[4]); \
  acc[5] = fmaf((wb).y, (sv), acc[5]); \
  acc[6] = fmaf((wb).z, (sv), acc[6]); \
  acc[7] = fmaf((wb).w, (sv), acc[7]); \
} while (0)

#define FMA4(acc, wa, sv) do { \
  acc[0] = fmaf((wa).x, (sv), acc[0]); \
  acc[1] = fmaf((wa).y, (sv), acc[1]); \
  acc[2] = fmaf((wa).z, (sv), acc[2]); \
  acc[3] = fmaf((wa).w, (sv), acc[3]); \
} while (0)

__device__ __forceinline__ float act_silu(float x) {
  return 1.679f * x / (1.0f + expf(-x));   // SILU_NORM * silu(x)
}

__device__ __forceinline__ short f2bf(float x) {
  __hip_bfloat16 h = __float2bfloat16(x);
  return *reinterpret_cast<short*>(&h);
}
__device__ __forceinline__ float bf2f(short s) {
  __hip_bfloat16 h = *reinterpret_cast<__hip_bfloat16*>(&s);
  return __bfloat162float(h);
}

// lane-linear permuted index for a 128n x 32k bf16 tile (shorts):
// frag read for channel-block nb = n>>4 is at nb*512 + (quad*16+m16)*8 + j
__device__ __forceinline__ int bperm(int n, int k) {
  return ((n >> 4) << 9) | (((((k >> 3) << 4) | (n & 15))) << 3) | (k & 7);
}

// ---------------------------------------------------------------------------
// K1: MLP -> weights -> mixed.  32 b per wg, 256 threads. (proven, unchanged)
// ---------------------------------------------------------------------------
__global__ __launch_bounds__(256) void k_prep(
    const float* __restrict__ s, const float* __restrict__ t2s,
    const float* __restrict__ w1, const float* __restrict__ w2,
    const float* __restrict__ w3, const float* __restrict__ gthr,
    float* __restrict__ mixed_ws)
{
  __shared__ float sT[64][36];    // [k][b], padded
  __shared__ float hT[256][36];   // [c][b], holds h1 then h2

  const int tid = threadIdx.x;
  const int b0  = blockIdx.x * 32;

  #pragma unroll
  for (int i = 0; i < 8; i++) {
    int flat = tid + i * 256;
    int bl = flat >> 6, k = flat & 63;
    sT[k][bl] = s[(size_t)(b0 + bl) * 64 + k];
  }
  __syncthreads();

  const int cg = tid & 31, bg = tid >> 5;
  const int c0 = cg * 8, bb0 = bg * 4;

  float acc[4][8];
  #pragma unroll
  for (int j = 0; j < 4; j++)
    #pragma unroll
    for (int i = 0; i < 8; i++) acc[j][i] = 0.f;

  for (int k = 0; k < 64; k++) {
    float4 bv = *(const float4*)&sT[k][bb0];
    float4 wa = *(const float4*)&w1[k * 256 + c0];
    float4 wb = *(const float4*)&w1[k * 256 + c0 + 4];
    const float bvv[4] = {bv.x, bv.y, bv.z, bv.w};
    #pragma unroll
    for (int j = 0; j < 4; j++) { FMA8(acc[j], wa, wb, bvv[j]); }
  }
  #pragma unroll
  for (int j = 0; j < 4; j++)
    #pragma unroll
    for (int i = 0; i < 8; i++)
      hT[c0 + i][bb0 + j] = act_silu(acc[j][i] * 0.125f);
  __syncthreads();

  float acc2[4][8];
  #pragma unroll
  for (int j = 0; j < 4; j++)
    #pragma unroll
    for (int i = 0; i < 8; i++) acc2[j][i] = 0.f;

  for (int k = 0; k < 256; k++) {
    float4 bv = *(const float4*)&hT[k][bb0];
    float4 wa = *(const float4*)&w2[k * 256 + c0];
    float4 wb = *(const float4*)&w2[k * 256 + c0 + 4];
    const float bvv[4] = {bv.x, bv.y, bv.z, bv.w};
    #pragma unroll
    for (int j = 0; j < 4; j++) { FMA8(acc2[j], wa, wb, bvv[j]); }
  }
  __syncthreads();
  #pragma unroll
  for (int j = 0; j < 4; j++)
    #pragma unroll
    for (int i = 0; i < 8; i++)
      hT[c0 + i][bb0 + j] = act_silu(acc2[j][i] * 0.0625f);
  __syncthreads();

  const int jj  = tid & 31;
  const int blg = tid >> 5;
  float acc3[4] = {0.f, 0.f, 0.f, 0.f};
  for (int k = 0; k < 256; k++) {
    float wv  = w3[k * 32 + jj];
    float4 hv = *(const float4*)&hT[k][blg * 4];
    acc3[0] = fmaf(hv.x, wv, acc3[0]);
    acc3[1] = fmaf(hv.y, wv, acc3[1]);
    acc3[2] = fmaf(hv.z, wv, acc3[2]);
    acc3[3] = fmaf(hv.w, wv, acc3[3]);
  }
  const float thrv = gthr[jj];
  #pragma unroll
  for (int r = 0; r < 4; r++) {
    int bl = blg * 4 + r;
    int b  = b0 + bl;
    float rel = acc3[r] * 0.0625f;
    const float* tp = t2s + (size_t)(b * 32 + jj) * 5;
    float tv0 = tp[0], tv1 = tp[1], tv2 = tp[2], tv3 = tp[3], tv4 = tp[4];
    float mag  = sqrtf(tv0*tv0 + tv1*tv1 + tv2*tv2 + tv3*tv3 + tv4*tv4);
    float gate = mag / (mag + thrv);
    float w = rel * gate * 0.17677669529663687f;  // 1/sqrt(32)
    float pm0 = w*tv0, pm1 = w*tv1, pm2 = w*tv2, pm3 = w*tv3, pm4 = w*tv4;
    #pragma unroll
    for (int off = 16; off >= 1; off >>= 1) {
      pm0 += __shfl_xor(pm0, off);
      pm1 += __shfl_xor(pm1, off);
      pm2 += __shfl_xor(pm2, off);
      pm3 += __shfl_xor(pm3, off);
      pm4 += __shfl_xor(pm4, off);
    }
    if (jj == 0) {
      float* mp = mixed_ws + (size_t)b * 5;
      mp[0] = pm0; mp[1] = pm1; mp[2] = pm2; mp[3] = pm3; mp[4] = pm4;
    }
  }
}

// ---------------------------------------------------------------------------
// K2: weight prep -> single B2 chunk stream (110 chunks of 4096 bf16 hi/lo),
// lane-linear fragment order via bperm(n,k). wSum = w2022 + w2202^T.
// ---------------------------------------------------------------------------
__global__ __launch_bounds__(256) void k_wprep(
    const float* __restrict__ w000,
    const float* __restrict__ w2022x,
    const float* __restrict__ w2202, float* __restrict__ wSum,
    const float* __restrict__ w022, const float* __restrict__ w202,
    const float* __restrict__ w222, const float* __restrict__ w220,
    short* __restrict__ B2h, short* __restrict__ B2l)
{
  const int tid = threadIdx.x;
  const int blk = blockIdx.x;
  if (blk < 64) {
    int u = blk;
    int base = u * 64 - (u * (u - 1)) / 2;
    int n = (64 - u) * 128;
    for (int idx = tid; idx < n; idx += 256) {
      int t = idx >> 7, wc = idx & 127;
      int v = u + t;
      int p = base + t;
      float val = w000[(size_t)(u * 64 + v) * 128 + wc];
      if (v > u) val += w000[(size_t)(v * 64 + u) * 128 + wc];
      size_t off = (size_t)(45 + (p >> 5)) * 4096 + bperm(wc, p & 31);
      short hs = f2bf(val);
      B2h[off] = hs;
      B2l[off] = f2bf(val - bf2f(hs));
    }
  } else if (blk < 128) {
    int idx = (blk - 64) * 256 + tid;  // 16384
    int u = idx >> 7, v = idx & 127;
    wSum[v * 128 + u] = w2022x[(size_t)v * 128 + u] + w2202[(size_t)u * 128 + v];
  } else {
    int c = blk - 128;                 // 0..44
    #pragma unroll
    for (int i = 0; i < 16; i++) {
      int e = i * 256 + tid;           // 0..4095 (target, permuted index)
      int nb = e >> 9;
      int ln = (e >> 3) & 63;
      int j  = e & 7;
      int w  = nb * 16 + (ln & 15);    // channel n
      int kk = ((ln >> 4) << 3) | j;   // K index 0..31
      float V = 0.f;
      if (c < 32) {
        int v = c >> 1, u = (c & 1) * 32 + kk;
        V = w022[(size_t)(u * 16 + v) * 128 + w]
          + w202[(size_t)(v * 64 + u) * 128 + w];
      } else if (c < 40) {
        int K = (c - 32) * 32 + kk;
        int u = K >> 4, v = K & 15;
        V = w222[(size_t)(u * 16 + v) * 128 + w];
      } else {
        int q = (c - 40) * 32 + kk;
        if (q < 136) {
          int u = 0;
          while ((u + 1) * 16 - ((u + 1) * u) / 2 <= q) u++;
          int base = u * 16 - (u * (u - 1)) / 2;
          int v = u + (q - base);
          V = w220[(size_t)(u * 16 + v) * 128 + w];
          if (v > u) V += w220[(size_t)(v * 16 + u) * 128 + w];
        }
      }
      short hs = f2bf(V);
      B2h[(size_t)c * 4096 + e] = hs;
      B2l[(size_t)c * 4096 + e] = f2bf(V - bf2f(hs));
    }
  }
}

// ---------------------------------------------------------------------------
// K_y2a: chunks 0..39 (merged 022/202 + 222) -> y2p. 256 blocks x 512 thr.
// 64-row LDS-staged structure (r21-proven, 85us, no spill).
// ---------------------------------------------------------------------------
__global__ __launch_bounds__(512) void k_y2a(
    const float* __restrict__ s, const float* __restrict__ t2s,
    const short* __restrict__ B2h, const short* __restrict__ B2l,
    unsigned short* __restrict__ y2p, Coefs cf)
{
  __shared__ float sL[64][68];                 // 17408 B
  __shared__ float tL[64][81];                 // 20736 B ([b][u*5+m])
  __shared__ __align__(16) short BhL[2][4096]; // 16384 B
  __shared__ __align__(16) short BlL[2][4096]; // 16384 B
  __shared__ float cL222[125];
  // ~71.4 KB

  const int tid  = threadIdx.x;
  const int b0   = blockIdx.x * 64;
  const int wave = tid >> 6;
  const int lane = tid & 63;
  const int m16  = lane & 15;
  const int quad = lane >> 4;
  const int bg   = wave & 3;
  const int nh   = wave >> 2;
  const int bloc = bg * 16 + m16;      // A-row (m) batch-local
  const int wbase = nh * 64;

  float dk022[5];
  #pragma unroll
  for (int k = 0; k < 5; k++) dk022[k] = cf.d022[k];

  // ---- stage s, t, c222 ----
  if (tid == 0) {
    #pragma unroll
    for (int i = 0; i < 125; i++) cL222[i] = cf.c222[i];
  }
  for (int idx = tid; idx < 4096; idx += 512) {
    int bl = idx >> 6, k = idx & 63;
    sL[bl][k] = s[(size_t)(b0 + bl) * 64 + k];
  }
  for (int idx = tid; idx < 5120; idx += 512) {
    int bl = idx / 80, rem = idx - bl * 80;
    int u = rem / 5, m = rem - u * 5;
    int b = b0 + bl;
    float v;
    if (u < 15) v = t2s[(size_t)(b * 32 + u) * 5 + m];
    else {
      v = 0.f;
      for (int kk = 0; kk < 32; kk++) v += t2s[(size_t)(b * 32 + kk) * 5 + m];
    }
    tL[bl][rem] = v;     // rem == u*5+m
  }
  __syncthreads();

  // preload chunk 0
  ((short8*)BhL[0])[tid] = ((const short8*)B2h)[tid];
  ((short8*)BlL[0])[tid] = ((const short8*)B2l)[tid];
  __syncthreads();

  f32x4 acc[5][4];
  #pragma unroll
  for (int k = 0; k < 5; k++)
    #pragma unroll
    for (int nf = 0; nf < 4; nf++) acc[k][nf] = 0.f;
  f32x4 p[4];    // P-slice accumulators (merged 022/202 path)
  #pragma unroll
  for (int nf = 0; nf < 4; nf++) p[nf] = 0.f;

  for (int c = 0; c < 40; c++) {
    const int cur = c & 1;
    if (c + 1 < 40) {
      ((short8*)BhL[cur ^ 1])[tid] = ((const short8*)(B2h + (size_t)(c + 1) * 4096))[tid];
      ((short8*)BlL[cur ^ 1])[tid] = ((const short8*)(B2l + (size_t)(c + 1) * 4096))[tid];
    }
    // B fragments for this chunk (lane-linear, conflict-free: 16B/lane)
    short8 bhv[4], blv[4];
    #pragma unroll
    for (int nf = 0; nf < 4; nf++) {
      const int nb = nh * 4 + nf;      // channel block (n>>4)
      bhv[nf] = *(const short8*)&BhL[cur][nb * 512 + lane * 8];
      blv[nf] = *(const short8*)&BlL[cur][nb * 512 + lane * 8];
    }

    if (c < 32) {
      // ---- merged 022+202: P[b,v,w] = sum_u Bsum[u,v,w] s[b,u] ----
      const int ks = c & 1;
      float sv[8];
      {
        float4 a = *(const float4*)&sL[bloc][ks * 32 + quad * 8];
        float4 b = *(const float4*)&sL[bloc][ks * 32 + quad * 8 + 4];
        sv[0]=a.x; sv[1]=a.y; sv[2]=a.z; sv[3]=a.w;
        sv[4]=b.x; sv[5]=b.y; sv[6]=b.z; sv[7]=b.w;
      }
      short8 ah, al;
      #pragma unroll
      for (int j = 0; j < 8; j++) {
        float x = sv[j];
        short hs = f2bf(x);
        ah[j] = hs;
        al[j] = f2bf(x - bf2f(hs));
      }
      #pragma unroll
      for (int nf = 0; nf < 4; nf++) {
        p[nf] = __builtin_amdgcn_mfma_f32_16x16x32_bf16(ah, bhv[nf], p[nf], 0, 0, 0);
        p[nf] = __builtin_amdgcn_mfma_f32_16x16x32_bf16(ah, blv[nf], p[nf], 0, 0, 0);
        p[nf] = __builtin_amdgcn_mfma_f32_16x16x32_bf16(al, bhv[nf], p[nf], 0, 0, 0);
      }
      if (ks == 1) {
        // contract over this v: acc[k] += d[k]*t[b,v,k]*P   (fp32)
        const int v = c >> 1;
        #pragma unroll
        for (int r = 0; r < 4; r++) {
          const int bl = bg * 16 + quad * 4 + r;   // D-row -> batch-local
          const float* tr = &tL[bl][v * 5];
          #pragma unroll
          for (int k = 0; k < 5; k++) {
            float f = dk022[k] * tr[k];
            #pragma unroll
            for (int nf = 0; nf < 4; nf++)
              acc[k][nf][r] += f * p[nf][r];
          }
        }
        #pragma unroll
        for (int nf = 0; nf < 4; nf++) p[nf] = 0.f;
      }
    } else {
      // ---- 222 segment: A_k = Q[b][u][v][k] built in-lane ----
      int cc = c - 32;
      int u  = cc * 2 + (quad >> 1);
      int vb = (quad & 1) * 8;
      float tu[5];
      #pragma unroll
      for (int i = 0; i < 5; i++) tu[i] = tL[bloc][u * 5 + i];
      float G[25];
      #pragma unroll
      for (int jk = 0; jk < 25; jk++) {
        float g = 0.f;
        #pragma unroll
        for (int i = 0; i < 5; i++)
          g = fmaf(cL222[i * 25 + jk], tu[i], g);
        G[jk] = g;
      }
      float av[5][8];
      #pragma unroll
      for (int j = 0; j < 8; j++) {
        float t5[5];
        #pragma unroll
        for (int j5 = 0; j5 < 5; j5++) t5[j5] = tL[bloc][(vb + j) * 5 + j5];
        #pragma unroll
        for (int k = 0; k < 5; k++) {
          float q = 0.f;
          #pragma unroll
          for (int j5 = 0; j5 < 5; j5++)
            q = fmaf(G[j5 * 5 + k], t5[j5], q);
          av[k][j] = q;
        }
      }
      #pragma unroll
      for (int k = 0; k < 5; k++) {
        short8 ah, al;
        #pragma unroll
        for (int j = 0; j < 8; j++) {
          float x = av[k][j];
          short hs = f2bf(x);
          ah[j] = hs;
          al[j] = f2bf(x - bf2f(hs));
        }
        #pragma unroll
        for (int nf = 0; nf < 4; nf++) {
          acc[k][nf] = __builtin_amdgcn_mfma_f32_16x16x32_bf16(ah, bhv[nf], acc[k][nf], 0, 0, 0);
          acc[k][nf] = __builtin_amdgcn_mfma_f32_16x16x32_bf16(ah, blv[nf], acc[k][nf], 0, 0, 0);
          acc[k][nf] = __builtin_amdgcn_mfma_f32_16x16x32_bf16(al, bhv[nf], acc[k][nf], 0, 0, 0);
        }
      }
    }
    __syncthreads();   // frag reads done AND next-chunk staging complete
  }

  // ---- epilogue: D row = quad*4+r (b-local in bg), col = m16 (ch-local) ----
  #pragma unroll
  for (int nf = 0; nf < 4; nf++) {
    int ch = wbase + nf * 16 + m16;
    #pragma unroll
    for (int r = 0; r < 4; r++) {
      int b = b0 + bg * 16 + quad * 4 + r;
      #pragma unroll
      for (int k = 0; k < 5; k++)
        y2p[((size_t)b * 5 + k) * 128 + ch] = (unsigned short)f2bf(acc[k][nf][r]);
    }
  }
}

// ---------------------------------------------------------------------------
// K_y0b: chunks 40..109 (220 gram + y000 sym pairs) -> y0w.
// (barrier-free 32-row structure, r23-proven)
// ---------------------------------------------------------------------------
__global__ __launch_bounds__(512) void k_y0b(
    const float* __restrict__ s, const float* __restrict__ t2s,
    const short* __restrict__ B2h, const short* __restrict__ B2l,
    float* __restrict__ y0w, Coefs cf)
{
  __shared__ float sL[32][65];                 // 8320 B
  __shared__ float tL[32][81];                 // 10368 B ([b][u*5+m])
  __shared__ unsigned char p136s[136];
  __shared__ unsigned short p16[2080];         // 4160 B
  // ~23 KB

  const int tid  = threadIdx.x;
  const int b0   = blockIdx.x * 32;
  const int wave = tid >> 6;
  const int lane = tid & 63;
  const int m16  = lane & 15;
  const int quad = lane >> 4;
  const int bg   = wave & 1;           // 0..1 (16-row groups)
  const int nh   = wave >> 1;          // 0..3 (32-channel groups)
  const int bloc = bg * 16 + m16;      // A-row (m) batch-local 0..31
  const int wbase = nh * 32;

  float dk220[5];
  #pragma unroll
  for (int k = 0; k < 5; k++) dk220[k] = cf.d220[k];

  // ---- stage s, t, pair tables (read-only after the single barrier) ----
  for (int idx = tid; idx < 2048; idx += 512) {
    int bl = idx >> 6, k = idx & 63;
    sL[bl][k] = s[(size_t)(b0 + bl) * 64 + k];
  }
  for (int idx = tid; idx < 2560; idx += 512) {
    int bl = idx / 80, rem = idx - bl * 80;
    int u = rem / 5, m = rem - u * 5;
    int b = b0 + bl;
    float v;
    if (u < 15) v = t2s[(size_t)(b * 32 + u) * 5 + m];
    else {
      v = 0.f;
      for (int kk = 0; kk < 32; kk++) v += t2s[(size_t)(b * 32 + kk) * 5 + m];
    }
    tL[bl][rem] = v;     // rem == u*5+m
  }
  if (tid < 16) {
    int u = tid;
    int base = u * 16 - (u * (u - 1)) / 2;
    for (int t = 0; t < 16 - u; t++)
      p136s[base + t] = (unsigned char)((u << 4) | (u + t));
  }
  if (tid < 64) {
    int u = tid;
    int base = u * 64 - (u * (u - 1)) / 2;
    for (int t = 0; t < 64 - u; t++)
      p16[base + t] = (unsigned short)((u << 8) | (u + t));
  }
  __syncthreads();   // the ONLY barrier

  f32x4 accY0[2];
  accY0[0] = 0.f; accY0[1] = 0.f;

  // B fragment addresses (short8 units): chunk c starts at c*512
  const short8* Bh8 = (const short8*)B2h;
  const short8* Bl8 = (const short8*)B2l;
  const int off0 = (nh * 2) * 64 + lane;   // nf=0 block
  const int off1 = off0 + 64;              // nf=1 block

  for (int c = 40; c < NCHUNK2; c++) {
    const size_t cb = (size_t)c * 512;
    short8 bh0 = Bh8[cb + off0];
    short8 bh1 = Bh8[cb + off1];
    short8 bl0 = Bl8[cb + off0];
    short8 bl1 = Bl8[cb + off1];

    short8 ah, al;
    if (c < 45) {
      // ---- 220 segment: A = gram of t (no k) ----
      int cc = c - 40;
      int qbase = cc * 32 + quad * 8;
      #pragma unroll
      for (int j = 0; j < 8; j++) {
        int q = qbase + j;
        float g = 0.f;
        if (q < 136) {
          int uv = p136s[q];
          int u = uv >> 4, v = uv & 15;
          #pragma unroll
          for (int m = 0; m < 5; m++)
            g = fmaf(dk220[m] * tL[bloc][u * 5 + m], tL[bloc][v * 5 + m], g);
        }
        short hs = f2bf(g);
        ah[j] = hs;
        al[j] = f2bf(g - bf2f(hs));
      }
    } else {
      // ---- y000 segment: A = s-pair products ----
      int pbase = (c - 45) * 32 + quad * 8;    // < 2080 always (65*32)
      #pragma unroll
      for (int j = 0; j < 8; j++) {
        int uv = p16[pbase + j];
        float x = sL[bloc][uv >> 8] * sL[bloc][uv & 255];
        short hs = f2bf(x);
        ah[j] = hs;
        al[j] = f2bf(x - bf2f(hs));
      }
    }
    accY0[0] = __builtin_amdgcn_mfma_f32_16x16x32_bf16(ah, bh0, accY0[0], 0, 0, 0);
    accY0[0] = __builtin_amdgcn_mfma_f32_16x16x32_bf16(ah, bl0, accY0[0], 0, 0, 0);
    accY0[0] = __builtin_amdgcn_mfma_f32_16x16x32_bf16(al, bh0, accY0[0], 0, 0, 0);
    accY0[1] = __builtin_amdgcn_mfma_f32_16x16x32_bf16(ah, bh1, accY0[1], 0, 0, 0);
    accY0[1] = __builtin_amdgcn_mfma_f32_16x16x32_bf16(ah, bl1, accY0[1], 0, 0, 0);
    accY0[1] = __builtin_amdgcn_mfma_f32_16x16x32_bf16(al, bh1, accY0[1], 0, 0, 0);
  }

  // ---- epilogue: D row = quad*4+r (b-local in bg), col = m16 (ch-local) ----
  #pragma unroll
  for (int nf = 0; nf < 2; nf++) {
    int ch = wbase + nf * 16 + m16;
    #pragma unroll
    for (int r = 0; r < 4; r++) {
      int b = b0 + bg * 16 + quad * 4 + r;
      y0w[(size_t)b * 128 + ch] = accY0[nf][r];
    }
  }
}

// ---------------------------------------------------------------------------
// K_fused: y0/y2 load + phase5 + epilogue. 32 b per block, 512 blocks,
// 512 threads. Merged 022/202 over wSum (one pass) + 222 K-tile-staged.
// ---------------------------------------------------------------------------
__global__ __launch_bounds__(512) void k_fused(
    const float* __restrict__ mixed_ws,
    const float* __restrict__ y0w, const unsigned short* __restrict__ y2p,
    const float* __restrict__ wSum, const float* __restrict__ w2222,
    const float* __restrict__ csc, float* __restrict__ out, Coefs cf)
{
  __shared__ __align__(16) float y0I[16][128][2];   // 16384 B
  __shared__ __align__(16) float wLd[32][128];      // 16384 B (K-tile stage)
  __shared__ float y2S[5][16][32][2];               // 20480 B (222 tile stage)
  __shared__ float cL222[125];
  __shared__ float corrAcc[32][5];
  __shared__ float pPL[32][25];
  // ~57.6 KB -> 2 blocks/CU

  const int tid = threadIdx.x;
  const int b0  = blockIdx.x * 32;

  float dk022[5];
  #pragma unroll
  for (int k = 0; k < 5; k++) dk022[k] = cf.d022[k];

  if (tid == 0) {
    #pragma unroll
    for (int i = 0; i < 125; i++) cL222[i] = cf.c222[i];
  }
  // stage y0 (a0-scaled) in interleaved-pair layout
  for (int idx = tid; idx < 4096; idx += 512) {
    int bl = idx >> 7, ch = idx & 127;
    y0I[bl >> 1][ch][bl & 1] = cf.a0 * y0w[(size_t)(b0 + bl) * 128 + ch];
  }

  const int xw = tid & 31;
  const int g  = tid >> 5;
  const int w0 = xw * 4;
  const int bA = 2 * g, bB = 2 * g + 1;
  const int srow = tid >> 4;            // 0..31 (wLd stage row)
  const int scol = (tid & 15) * 8;      // 0..120 (wLd stage col)

  // y2 fragments from ws (bf16), a2-scaled
  float y2acc[5][2][4];
  #pragma unroll
  for (int k = 0; k < 5; k++) {
    #pragma unroll
    for (int h = 0; h < 2; h++) {
      int b = b0 + 2 * g + h;
      const unsigned short* yp = y2p + ((size_t)b * 5 + k) * 128 + w0;
      ushort4 u4 = *(const ushort4*)yp;
      y2acc[k][h][0] = cf.a2 * bf2f((short)u4.x);
      y2acc[k][h][1] = cf.a2 * bf2f((short)u4.y);
      y2acc[k][h][2] = cf.a2 * bf2f((short)u4.z);
      y2acc[k][h][3] = cf.a2 * bf2f((short)u4.w);
    }
  }
  __syncthreads();   // y0I ready

  // ================= phase 5 — K-tile-staged =================
  // merged 022+202 path (wSum = w2022 + w2202^T; d022 == d202)
  {
    float gvr[2][4] = {{0.f,0.f,0.f,0.f},{0.f,0.f,0.f,0.f}};
    for (int t = 0; t < 4; t++) {
      const int u0 = t * 32;
      *(float4*)&wLd[srow][scol]     = *(const float4*)(wSum + (size_t)(u0 + srow) * 128 + scol);
      *(float4*)&wLd[srow][scol + 4] = *(const float4*)(wSum + (size_t)(u0 + srow) * 128 + scol + 4);
      __syncthreads();
      #pragma unroll 8
      for (int uu = 0; uu < 32; uu++) {
        float2 y0p = *(const float2*)&y0I[g][u0 + uu][0];
        float4 w4 = *(const float4*)&wLd[uu][w0];
        FMA4(gvr[0], w4, y0p.x);
        FMA4(gvr[1], w4, y0p.y);
      }
      __syncthreads();
    }
    #pragma unroll
    for (int k = 0; k < 5; k++) {
      float pA = gvr[0][0]*y2acc[k][0][0] + gvr[0][1]*y2acc[k][0][1]
               + gvr[0][2]*y2acc[k][0][2] + gvr[0][3]*y2acc[k][0][3];
      float pB = gvr[1][0]*y2acc[k][1][0] + gvr[1][1]*y2acc[k][1][1]
               + gvr[1][2]*y2acc[k][1][2] + gvr[1][3]*y2acc[k][1][3];
      pA += __shfl_xor(pA, 16); pA += __shfl_xor(pA, 8); pA += __shfl_xor(pA, 4);
      pA += __shfl_xor(pA, 2);  pA += __shfl_xor(pA, 1);
      pB += __shfl_xor(pB, 16); pB += __shfl_xor(pB, 8); pB += __shfl_xor(pB, 4);
      pB += __shfl_xor(pB, 2);  pB += __shfl_xor(pB, 1);
      if (xw == 0) {
        corrAcc[bA][k] = dk022[k] * pA;
        corrAcc[bB][k] = dk022[k] * pB;
      }
    }
  }
  // 222 path: all 5 zr[i] accumulated per w2222-tile; y2S per-tile stage
  {
    float zr[5][2][4];
    #pragma unroll
    for (int i = 0; i < 5; i++)
      #pragma unroll
      for (int h = 0; h < 2; h++)
        #pragma unroll
        for (int w = 0; w < 4; w++) zr[i][h][w] = 0.f;

    for (int t = 0; t < 4; t++) {
      const int u0 = t * 32;
      *(float4*)&wLd[srow][scol]     = *(const float4*)(w2222 + (size_t)(u0 + srow) * 128 + scol);
      *(float4*)&wLd[srow][scol + 4] = *(const float4*)(w2222 + (size_t)(u0 + srow) * 128 + scol + 4);
      if (w0 >= u0 && w0 < u0 + 32) {
        const int uu0 = w0 - u0;
        #pragma unroll
        for (int i = 0; i < 5; i++)
          #pragma unroll
          for (int h = 0; h < 2; h++)
            #pragma unroll
            for (int c = 0; c < 4; c++)
              y2S[i][g][uu0 + c][h] = y2acc[i][h][c];
      }
      __syncthreads();
      #pragma unroll 4
      for (int uu = 0; uu < 32; uu++) {
        float4 w4 = *(const float4*)&wLd[uu][w0];
        #pragma unroll
        for (int i = 0; i < 5; i++) {
          float ya = y2S[i][g][uu][0];
          float yb = y2S[i][g][uu][1];
          FMA4(zr[i][0], w4, ya);
          FMA4(zr[i][1], w4, yb);
        }
      }
      __syncthreads();
    }
    #pragma unroll
    for (int i = 0; i < 5; i++) {
      #pragma unroll
      for (int j = 0; j < 5; j++) {
        float pA = zr[i][0][0]*y2acc[j][0][0] + zr[i][0][1]*y2acc[j][0][1]
                 + zr[i][0][2]*y2acc[j][0][2] + zr[i][0][3]*y2acc[j][0][3];
        float pB = zr[i][1][0]*y2acc[j][1][0] + zr[i][1][1]*y2acc[j][1][1]
                 + zr[i][1][2]*y2acc[j][1][2] + zr[i][1][3]*y2acc[j][1][3];
        pA += __shfl_xor(pA, 16); pA += __shfl_xor(pA, 8); pA += __shfl_xor(pA, 4);
        pA += __shfl_xor(pA, 2);  pA += __shfl_xor(pA, 1);
        pB += __shfl_xor(pB, 16); pB += __shfl_xor(pB, 8); pB += __shfl_xor(pB, 4);
        pB += __shfl_xor(pB, 2);  pB += __shfl_xor(pB, 1);
        if (xw == 0) {
          pPL[bA][i * 5 + j] = pA;
          pPL[bB][i * 5 + j] = pB;
        }
      }
    }
  }
  __syncthreads();   // corrAcc/pPL visible to epilogue threads

  // ---- epilogue ----
  if (tid < 160) {
    int bb = tid / 5, k = tid - bb * 5;
    float c2 = 0.f;
    #pragma unroll
    for (int ii = 0; ii < 5; ii++)
      #pragma unroll
      for (int jj = 0; jj < 5; jj++)
        c2 = fmaf(cL222[ii * 25 + jj * 5 + k], pPL[bb][ii * 5 + jj], c2);
    float tot = corrAcc[bb][k] + c2;
    int b = b0 + bb;
    out[(size_t)b * 5 + k] = mixed_ws[(size_t)b * 5 + k] + csc[0] * cf.b2 * tot;
  }
}

// ---------------------------------------------------------------------------
// Host: replicate reference's wigner-3j computation (RREF null space).
// ---------------------------------------------------------------------------
namespace {

using cplx = std::complex<double>;

static void su2_gen(int l, std::vector<cplx>& Jx, std::vector<cplx>& Jy,
                    std::vector<cplx>& Jz) {
  int d = 2 * l + 1;
  Jx.assign((size_t)d * d, cplx(0, 0));
  Jy.assign((size_t)d * d, cplx(0, 0));
  Jz.assign((size_t)d * d, cplx(0, 0));
  for (int a = 0; a < d; a++) Jz[(size_t)a * d + a] = cplx(a - l, 0);
  for (int r = 1; r < d; r++) {
    double m = (r - 1) - l;
    double v = std::sqrt(l * (l + 1.0) - m * (m + 1.0));
    Jx[(size_t)r * d + (r - 1)] += cplx(v / 2, 0);
    Jx[(size_t)(r - 1) * d + r] += cplx(v / 2, 0);
    Jy[(size_t)r * d + (r - 1)] += cplx(0, -v / 2);
    Jy[(size_t)(r - 1) * d + r] += cplx(0, v / 2);
  }
}

static void real_basis(int l, std::vector<cplx>& U) {
  int d = 2 * l + 1;
  U.assign((size_t)d * d, cplx(0, 0));
  U[(size_t)l * d + l] = cplx(1, 0);
  double is2 = 1.0 / std::sqrt(2.0);
  for (int m = 1; m <= l; m++) {
    double sgn = (m % 2 == 0) ? 1.0 : -1.0;
    U[(size_t)(l + m) * d + (l + m)] = cplx(sgn * is2, 0);
    U[(size_t)(l + m) * d + (l - m)] = cplx(is2, 0);
    U[(size_t)(l - m) * d + (l - m)] = cplx(0, is2);
    U[(size_t)(l - m) * d + (l + m)] = cplx(0, -sgn * is2);
  }
}

static void real_gens(int l, std::vector<double> G[3]) {
  int d = 2 * l + 1;
  if (l == 0) { for (int a = 0; a < 3; a++) G[a].assign(1, 0.0); return; }
  std::vector<cplx> J[3];
  su2_gen(l, J[0], J[1], J[2]);
  std::vector<cplx> U;
  real_basis(l, U);
  for (int a = 0; a < 3; a++) {
    std::vector<cplx> T((size_t)d * d, cplx(0, 0));
    for (int i = 0; i < d; i++)
      for (int k = 0; k < d; k++) {
        cplx s(0, 0);
        for (int j = 0; j < d; j++)
          s += U[(size_t)i * d + j] * (cplx(0, -1) * J[a][(size_t)j * d + k]);
        T[(size_t)i * d + k] = s;
      }
    G[a].assign((size_t)d * d, 0.0);
    for (int i = 0; i < d; i++)
      for (int k = 0; k < d; k++) {
        cplx s(0, 0);
        for (int j = 0; j < d; j++)
          s += T[(size_t)i * d + j] * std::conj(U[(size_t)k * d + j]);
        G[a][(size_t)i * d + k] = s.real();
      }
  }
}

static void w3j_host(int l1, int l2, int l3, float* out) {
  int d1 = 2 * l1 + 1, d2 = 2 * l2 + 1, d3 = 2 * l3 + 1;
  int D = d1 * d2 * d3;
  std::vector<double> G1[3], G2[3], G3[3];
  real_gens(l1, G1); real_gens(l2, G2); real_gens(l3, G3);
  int R = 3 * D;
  std::vector<double> M((size_t)R * D, 0.0);
  for (int a = 0; a < 3; a++) {
    double* Ma = &M[(size_t)a * D * D];
    for (int i1 = 0; i1 < d1; i1++)
      for (int j1 = 0; j1 < d1; j1++) {
        double g = G1[a][(size_t)i1 * d1 + j1];
        if (g == 0.0) continue;
        for (int i2 = 0; i2 < d2; i2++)
          for (int i3 = 0; i3 < d3; i3++)
            Ma[(size_t)((i1 * d2 + i2) * d3 + i3) * D + ((j1 * d2 + i2) * d3 + i3)] += g;
      }
    for (int i2 = 0; i2 < d2; i2++)
      for (int j2 = 0; j2 < d2; j2++) {
        double g = G2[a][(size_t)i2 * d2 + j2];
        if (g == 0.0) continue;
        for (int i1 = 0; i1 < d1; i1++)
          for (int i3 = 0; i3 < d3; i3++)
            Ma[(size_t)((i1 * d2 + i2) * d3 + i3) * D + ((i1 * d2 + j2) * d3 + i3)] += g;
      }
    for (int i3 = 0; i3 < d3; i3++)
      for (int j3 = 0; j3 < d3; j3++) {
        double g = G3[a][(size_t)i3 * d3 + j3];
        if (g == 0.0) continue;
        for (int i1 = 0; i1 < d1; i1++)
          for (int i2 = 0; i2 < d2; i2++)
            Ma[(size_t)((i1 * d2 + i2) * d3 + i3) * D + ((i1 * d2 + i2) * d3 + j3)] += g;
      }
  }
  std::vector<int> pivcol;
  int rank = 0;
  for (int col = 0; col < D && rank < R; col++) {
    int pr = -1; double pv = 1e-9;
    for (int r = rank; r < R; r++) {
      double av = std::fabs(M[(size_t)r * D + col]);
      if (av > pv) { pv = av; pr = r; }
    }
    if (pr < 0) continue;
    if (pr != rank)
      for (int c = 0; c < D; c++) std::swap(M[(size_t)pr * D + c], M[(size_t)rank * D + c]);
    double inv = 1.0 / M[(size_t)rank * D + col];
    for (int c = 0; c < D; c++) M[(size_t)rank * D + c] *= inv;
    for (int r = 0; r < R; r++) {
      if (r == rank) continue;
      double f = M[(size_t)r * D + col];
      if (f != 0.0)
        for (int c = 0; c < D; c++) M[(size_t)r * D + c] -= f * M[(size_t)rank * D + c];
    }
    pivcol.push_back(col);
    rank++;
  }
  std::vector<char> isp(D, 0);
  for (int c : pivcol) isp[c] = 1;
  int fc = 0;
  for (int c = 0; c < D; c++) if (!isp[c]) { fc = c; break; }
  std::vector<double> x(D, 0.0);
  x[fc] = 1.0;
  for (int r = 0; r < rank; r++) x[pivcol[r]] = -M[(size_t)r * D + fc];
  double n = 0;
  for (double v : x) n += v * v;
  n = std::sqrt(n);
  for (int c = 0; c < D; c++) x[c] /= n;
  double best = 0;
  for (int c = 0; c < D; c++) { double av = std::fabs(x[c]); if (av > best) best = av; }
  double ssum = 0;
  for (int c = 0; c < D; c++) {
    double av = std::fabs(x[c]);
    if (av >= best * 0.999) ssum += (x[c] >= 0 ? 1.0 : -1.0);
  }
  double sgn = (ssum >= 0) ? 1.0 : -1.0;
  for (int c = 0; c < D; c++) out[c] = (float)(x[c] * sgn);
}

}  // namespace

// ---------------------------------------------------------------------------
extern "C" void kernel_launch(void* const* d_in, const int* in_sizes, int n_in,
                              void* d_out, int out_size, void* d_ws, size_t ws_size,
                              hipStream_t stream)
{
  (void)in_sizes; (void)n_in; (void)out_size; (void)ws_size;

  const float* s     = (const float*)d_in[0];
  const float* t2s   = (const float*)d_in[1];
  const float* w1    = (const float*)d_in[2];
  const float* w2    = (const float*)d_in[3];
  const float* w3    = (const float*)d_in[4];
  const float* gthr  = (const float*)d_in[5];
  const float* w000  = (const float*)d_in[6];
  const float* w220  = (const float*)d_in[7];
  const float* w022  = (const float*)d_in[8];
  const float* w202  = (const float*)d_in[9];
  const float* w222  = (const float*)d_in[10];
  const float* w2022 = (const float*)d_in[11];
  const float* w2202 = (const float*)d_in[12];
  const float* w2222 = (const float*)d_in[13];
  const float* csc   = (const float*)d_in[14];
  float* out = (float*)d_out;

  char* ws = (char*)d_ws;
  float* mixed_ws = (float*)(ws + MIX_WS_OFF);
  float* wSum     = (float*)(ws + W202T_OFF);
  short* B2h      = (short*)(ws + B2H_OFF);
  short* B2l      = (short*)(ws + B2L_OFF);
  float* y0_ws    = (float*)(ws + Y0_WS_OFF);
  unsigned short* y2p = (unsigned short*)(ws + Y2P_OFF);

  Coefs cf;
  {
    float c000v[1], c022v[25], c202v[25], c220v[25];
    w3j_host(0, 0, 0, c000v);
    w3j_host(0, 2, 2, c022v);
    w3j_host(2, 0, 2, c202v);
    w3j_host(2, 2, 0, c220v);
    w3j_host(2, 2, 2, cf.c222);
    for (int i = 0; i < 125; i++) cf.c222[i] *= C222_FLIP;
    for (int k = 0; k < 5; k++) {
      cf.d022[k] = c022v[k * 5 + k];
      cf.d202[k] = c202v[k * 5 + k];
      cf.d220[k] = c220v[k * 5 + k];
    }
    (void)c000v;
    cf.a0 = (float)std::sqrt(1.0 / (64.0 * 64.0 + 16.0 * 16.0));
    cf.a2 = (float)std::sqrt(5.0 / (2.0 * 64.0 * 16.0 + 16.0 * 16.0));
    cf.b2 = (float)std::sqrt(5.0 / (3.0 * 128.0 * 128.0));
  }

  hipLaunchKernelGGL(k_prep, dim3(512), dim3(256), 0, stream,
                     s, t2s, w1, w2, w3, gthr, mixed_ws);
  hipLaunchKernelGGL(k_wprep, dim3(173), dim3(256), 0, stream,
                     w000, w2022, w2202, wSum,
                     w022, w202, w222, w220, B2h, B2l);
  hipLaunchKernelGGL(k_y0b, dim3(512), dim3(512), 0, stream,
                     s, t2s, B2h, B2l, y0_ws, cf);
  hipLaunchKernelGGL(k_y2a, dim3(256), dim3(512), 0, stream,
                     s, t2s, B2h, B2l, y2p, cf);
  hipLaunchKernelGGL(k_fused, dim3(512), dim3(512), 0, stream,
                     mixed_ws, y0_ws, y2p, wSum, w2222, csc, out, cf);
}